// Round 2
// 113.017 us; speedup vs baseline: 1.0550x; 1.0550x over previous
//
#include <hip/hip_runtime.h>

typedef unsigned long long u64;

// B = 64 == wavefront size; lane = batch index throughout.
// N = 20000 = NG*GSZ, E = 1,280,000 = NG*ETILE. TWO kernels, NO memset.
//   k1 scatter: block g transposes its 40 nodes (x -> xTh bf16) AND bucket-
//      sorts its 2560 edges by dst-group in LDS; flush is a CONTIGUOUS 20KB
//      stream into packed[g*ETILE ...] (deterministic placement — the old
//      gcur global cursor atomics, 250K contended fetch-adds on 32 cache
//      lines, are GONE). Per-block bucket offsets go to goff[g][512].
//   k2 sortreduce: block g gathers its records from 500 runs (prefix-scan of
//      run lengths + 9-step binary search per slot -> mostly-coalesced run
//      reads), histograms keys carrying the RANK in registers (no second
//      placement pass, no rec[] buffer: LDS 70.5 -> ~53 KB), LDS placement
//      into rec2, then the PROVEN wave-per-node REGISTER reduce (8-deep
//      independent bf16 gathers), LDS-transposed coalesced epilogue.
// Lessons: no per-record LDS atomics in accumulate (R4/R5 ~300cy); register
// acc + batched gathers (R3/R6); contiguous flush beats run-coalesced
// scattered flush (R12: scatter VALUBusy was 0.67% = stalled on gcur
// atomics + partial-line writes); grid ~ 2x256 CUs (R9); no cooperative
// grid.sync (R10: ~350us); total HBM traffic ~50MB => latency/issue-bound.

#define GSZ   40
#define NG    500
#define CAP   4096    // records per k2 block; mean 2560, +30 sigma headroom
#define ETILE 2560    // 512 threads * 5 edges; NG*ETILE == E
#define NBIN  512     // key = dl*8 | (src>>12); dl<40, band<5 -> key<320

__device__ __forceinline__ unsigned short f32_to_bf16(float f) {
    unsigned int u = __float_as_uint(f);
    u += 0x7FFFu + ((u >> 16) & 1u);   // round-to-nearest-even
    return (unsigned short)(u >> 16);
}

__device__ __forceinline__ int wave_incl_scan(int v, int lane) {
#pragma unroll
    for (int d = 1; d < 64; d <<= 1) {
        int u = __shfl_up(v, d, 64);
        if (lane >= d) v += u;
    }
    return v;
}

__global__ __launch_bounds__(512) void scatter_kernel(
        const float* __restrict__ x, const float* __restrict__ adj,
        const float* __restrict__ w, const int* __restrict__ src,
        const int* __restrict__ dst, unsigned short* __restrict__ xTh,
        int* __restrict__ goff, u64* __restrict__ packed, int N, int E) {
    __shared__ float tile[64][GSZ + 1];     // 10.5 KB
    __shared__ u64 staged[ETILE];           // 20 KB
    __shared__ int cnt[NBIN];
    __shared__ int ofs[NBIN];
    __shared__ int wtot[8], wbase[8];       // ~35 KB total -> 4 blocks/CU
    int t = threadIdx.x, g = blockIdx.x;
    int lane = t & 63, wv = t >> 6;

    // (a) transpose this group's 40 node columns: x[b][n] -> xTh[n][b] bf16
    int n0 = g * GSZ;
    for (int lin = t; lin < 64 * GSZ; lin += 512) {
        int nl = lin % GSZ, b = lin / GSZ;          // consecutive t -> 160B runs
        int n = n0 + nl;
        tile[b][nl] = (n < N) ? x[(long)b * N + n] : 0.f;
    }
    cnt[t] = 0;
    __syncthreads();
    for (int lin = t; lin < 64 * GSZ; lin += 512) {
        int b = lin & 63, nl = lin >> 6;            // consecutive t -> 128B runs
        int n = n0 + nl;
        if (n < N) xTh[(long)n * 64 + b] = f32_to_bf16(tile[b][nl]);
    }

    // (b) bucket-count this block's 2560 edges; rank carried in registers
    int base = g * ETILE;
    u64 pk[5]; int gk[5]; int rk[5];
#pragma unroll
    for (int k = 0; k < 5; ++k) {
        int e = base + k * 512 + t;
        int gg; u64 p;
        if (e < E) {
            int d = dst[e];
            float c = adj[e] * w[e];
            gg = d / GSZ;                           // magic-mul (constant)
            // record: coef (hi32) | src<<6 | dstLocal (lo32)
            p = ((u64)__float_as_uint(c) << 32)
              | (u64)(((unsigned int)src[e] << 6) | (unsigned int)(d - gg * GSZ));
        } else { gg = NBIN - 1; p = 0; }
        pk[k] = p; gk[k] = gg;
        rk[k] = atomicAdd(&cnt[gg], 1);
    }
    __syncthreads();

    // (c) exclusive scan of 512 bins: wave shfl-scan + 8-way fixup
    int c = cnt[t];
    int incl = wave_incl_scan(c, lane);
    if (lane == 63) wtot[wv] = incl;
    __syncthreads();
    if (t == 0) {
        int run = 0;
#pragma unroll
        for (int k = 0; k < 8; ++k) { wbase[k] = run; run += wtot[k]; }
    }
    __syncthreads();
    ofs[t] = wbase[wv] + incl - c;                  // exclusive
    __syncthreads();

    // (d) stage ordered by bucket; publish offsets; contiguous flush
#pragma unroll
    for (int k = 0; k < 5; ++k) {
        int pos = ofs[gk[k]] + rk[k];
        staged[pos] = pk[k];
    }
    goff[g * NBIN + t] = ofs[t];                    // 2KB coalesced row
    __syncthreads();
    long obase = (long)g * ETILE;
#pragma unroll
    for (int k = 0; k < 5; ++k)                     // 20KB pure stream, no atomics
        packed[obase + k * 512 + t] = staged[k * 512 + t];
}

__global__ __launch_bounds__(1024) void sortreduce_kernel(
        const u64* __restrict__ packed, const int* __restrict__ goff,
        const unsigned short* __restrict__ xTh, const float* __restrict__ x,
        const float* __restrict__ self_w, const float* __restrict__ bias,
        float* __restrict__ out, int N) {
    __shared__ u64 rec2[CAP];          // 32 KB
    __shared__ float sacc[GSZ * 65];   // 10.4 KB (separate now; rec[] deleted)
    __shared__ int rstart[NG];         // per-source-block run start (2 KB)
    __shared__ int rpos[NBIN];         // prefix of run lengths (rpos[511]=m)
    __shared__ int hist[NBIN];
    __shared__ int hoff[NBIN + 1];
    __shared__ int wtot[8], wbase[8];  // ~53 KB total -> 2 blocks/CU (thread cap)
    int t = threadIdx.x, g = blockIdx.x;
    int lane = t & 63, wv = t >> 6;

    // run table: block j's records for group g live at
    // packed[j*ETILE + goff[j][g] ... goff[j][g+1])
    if (t < NBIN) hist[t] = 0;
    int c = 0;
    if (t < NG) {
        int s0 = goff[t * NBIN + g];
        int s1 = goff[t * NBIN + g + 1];
        rstart[t] = s0;
        c = s1 - s0;
    }
    int incl = wave_incl_scan(c, lane);
    if (t < NBIN && lane == 63) wtot[wv] = incl;
    __syncthreads();
    if (t == 0) {
        int run = 0;
#pragma unroll
        for (int k = 0; k < 8; ++k) { wbase[k] = run; run += wtot[k]; }
    }
    __syncthreads();
    if (t < NBIN) rpos[t] = wbase[wv] + incl - c;
    __syncthreads();
    int m = min(rpos[NBIN - 1], CAP);  // bins 500..510 empty -> rpos[511]=total

    // gather records from runs + histogram keys; RANK stays in registers
    u64 pv[4]; int rk4[4];
#pragma unroll
    for (int k = 0; k < 4; ++k) {
        int i = (k << 10) + t;
        pv[k] = 0; rk4[k] = -1;
        if (i < m) {
            int lo = 0;                 // largest j with rpos[j] <= i (9 steps)
#pragma unroll
            for (int s = 256; s >= 1; s >>= 1) {
                int j = lo + s;
                if (j < NG && rpos[j] <= i) lo = j;
            }
            u64 p = packed[(long)lo * ETILE + rstart[lo] + (i - rpos[lo])];
            pv[k] = p;
            unsigned int lo32 = (unsigned int)p;
            int key = (int)((lo32 & 63u) << 3) | (int)(lo32 >> 18);
            rk4[k] = atomicAdd(&hist[key], 1);
        }
    }
    __syncthreads();

    // exclusive scan of 512 key bins
    c = (t < NBIN) ? hist[t] : 0;
    incl = wave_incl_scan(c, lane);
    if (t < NBIN && lane == 63) wtot[wv] = incl;
    __syncthreads();
    if (t == 0) {
        int run = 0;
#pragma unroll
        for (int k = 0; k < 8; ++k) { wbase[k] = run; run += wtot[k]; }
        hoff[NBIN] = m;
    }
    __syncthreads();
    if (t < NBIN) hoff[t] = wbase[wv] + incl - c;
    __syncthreads();

    // placement straight from registers: no atomics, no rec[] re-read
#pragma unroll
    for (int k = 0; k < 4; ++k) {
        if (rk4[k] >= 0) {
            u64 p = pv[k];
            unsigned int lo32 = (unsigned int)p;
            int key = (int)((lo32 & 63u) << 3) | (int)(lo32 >> 18);
            rec2[hoff[key] + rk4[k]] = (p & 0xFFFFFFFF00000000ull) | (u64)(lo32 >> 6);
        }
    }
    __syncthreads();

    // reduce: 16 waves; wave handles dl = wave, wave+16, wave+32; REGISTER acc
    for (int dl = wv; dl < GSZ; dl += 16) {
        int r0 = hoff[dl << 3];        // wave-uniform LDS broadcast
        int r1 = hoff[(dl << 3) + 8];
        float a0 = 0.f, a1 = 0.f;
        int r = r0;
        for (; r + 8 <= r1; r += 8) {
            u64 p[8];
#pragma unroll
            for (int k = 0; k < 8; ++k) p[k] = rec2[r + k];
            float gg[8];
#pragma unroll
            for (int k = 0; k < 8; ++k) {
                int sk = (int)(unsigned int)p[k];
                float ck = __uint_as_float((unsigned int)(p[k] >> 32));
                float xv = __uint_as_float((unsigned int)xTh[sk * 64 + lane] << 16);
                gg[k] = ck * xv;       // 8 independent 128B bf16 gathers
            }
            a0 += (gg[0] + gg[1]) + (gg[2] + gg[3]);
            a1 += (gg[4] + gg[5]) + (gg[6] + gg[7]);
        }
        for (; r < r1; ++r) {
            u64 p = rec2[r];
            int sk = (int)(unsigned int)p;
            float ck = __uint_as_float((unsigned int)(p >> 32));
            float xv = __uint_as_float((unsigned int)xTh[sk * 64 + lane] << 16);
            a0 += ck * xv;
        }
        sacc[dl * 65 + lane] = a0 + a1;   // direct; sacc no longer aliases rec
    }
    __syncthreads();

    // epilogue: n = g*GSZ + lane (lane<40 active); 4 batch rows per wave
    int nl = lane;
    int n = g * GSZ + nl;
    bool ok = (nl < GSZ) && (n < N);
    float sl = 0.f, bi = 0.f;
    if (ok) { sl = x[n] * self_w[n]; bi = bias[n]; }  // x row 0 (ref quirk)
#pragma unroll
    for (int i = 0; i < 4; ++i) {
        int b = wv * 4 + i;
        if (ok) {
            float v = sacc[nl * 65 + b] * sl + bi;
            out[(long)b * N + n] = fmaxf(v, 0.f);     // 160B runs
        }
    }
}

extern "C" void kernel_launch(void* const* d_in, const int* in_sizes, int n_in,
                              void* d_out, int out_size, void* d_ws, size_t ws_size,
                              hipStream_t stream) {
    const float* x      = (const float*)d_in[0];
    const float* adj    = (const float*)d_in[1];
    const float* w      = (const float*)d_in[2];
    const float* self_w = (const float*)d_in[3];
    const float* bias   = (const float*)d_in[4];
    const int*   src    = (const int*)d_in[5];
    const int*   dst    = (const int*)d_in[6];

    int N = in_sizes[3];            // 20000 == NG*GSZ
    int E = in_sizes[1];            // 1,280,000 == NG*ETILE
    (void)n_in; (void)ws_size; (void)out_size;

    // workspace: packed (10.24 MB), bf16 xTh (2.56 MB), goff (1 MB)
    u64*            packed = (u64*)d_ws;                          // NG*ETILE
    unsigned short* xTh    = (unsigned short*)(packed + (size_t)NG * ETILE);
    int*            goff   = (int*)(xTh + (size_t)N * 64);        // NG*NBIN
    float*          out    = (float*)d_out;

    hipLaunchKernelGGL(scatter_kernel, dim3(NG), dim3(512), 0, stream,
                       x, adj, w, src, dst, xTh, goff, packed, N, E);
    hipLaunchKernelGGL(sortreduce_kernel, dim3(NG), dim3(1024), 0, stream,
                       packed, goff, xTh, x, self_w, bias, out, N);
}